// Round 5
// baseline (291.924 us; speedup 1.0000x reference)
//
#include <hip/hip_runtime.h>
#include <hip/hip_cooperative_groups.h>

namespace cg = cooperative_groups;

// RSNorm: x (131072 x 256) f32 -> column mean/var -> normalize.
// Round-4: fuse the 3 passes into ONE cooperative kernel (2 grid syncs replace
// 2 kernel-boundary drains + the pass-2 dispatch). 1024 blocks x 256 threads
// (4 waves/block -> <=2048 co-resident blocks, so 1024 is safely co-resident).

static constexpr int   D         = 256;
static constexpr int   NROWS     = 131072;
static constexpr float EPS       = 1e-5f;
static constexpr float VAR_FLOOR = 0.001f;

static constexpr int NBLK         = 1024;
static constexpr int ROWS_PER_BLK = NROWS / NBLK;        // 128
static constexpr int P1_ITERS     = ROWS_PER_BLK / 4;    // 32
static constexpr int P3_TRIPS     = (NROWS * (D / 4)) / (NBLK * 256); // 32
static constexpr size_t P3_STRIDE = (size_t)NBLK * 256;  // 262144 (mult of 64)

typedef float f4 __attribute__((ext_vector_type(4)));

__global__ __launch_bounds__(256) void rsnorm_fused(const float* __restrict__ x,
                                                    float* __restrict__ psum,
                                                    float* __restrict__ psq,
                                                    float* __restrict__ stats,
                                                    float* __restrict__ out) {
    const int tid    = threadIdx.x;
    const int bid    = blockIdx.x;
    const int col4   = tid & 63;   // which float4 of the row
    const int rowoff = tid >> 6;   // 0..3
    const f4* __restrict__ xv = (const f4*)x;

    // ---- Phase 1: partial column sums over this block's 128 rows ----
    {
        const size_t base_row = (size_t)bid * ROWS_PER_BLK + rowoff;
        f4 s = (f4)0.f;
        f4 q = (f4)0.f;
        #pragma unroll 8
        for (int i = 0; i < P1_ITERS; ++i) {
            f4 v = xv[(base_row + (size_t)i * 4) * (D / 4) + col4];
            s += v;
            q.x = fmaf(v.x, v.x, q.x);
            q.y = fmaf(v.y, v.y, q.y);
            q.z = fmaf(v.z, v.z, q.z);
            q.w = fmaf(v.w, v.w, q.w);
        }
        __shared__ float ls[4][D];
        __shared__ float lq[4][D];
        ls[rowoff][col4 * 4 + 0] = s.x;
        ls[rowoff][col4 * 4 + 1] = s.y;
        ls[rowoff][col4 * 4 + 2] = s.z;
        ls[rowoff][col4 * 4 + 3] = s.w;
        lq[rowoff][col4 * 4 + 0] = q.x;
        lq[rowoff][col4 * 4 + 1] = q.y;
        lq[rowoff][col4 * 4 + 2] = q.z;
        lq[rowoff][col4 * 4 + 3] = q.w;
        __syncthreads();
        // thread tid reduces column tid across the 4 row-lanes, stores transposed
        float fs = ls[0][tid] + ls[1][tid] + ls[2][tid] + ls[3][tid];
        float fq = lq[0][tid] + lq[1][tid] + lq[2][tid] + lq[3][tid];
        psum[(size_t)tid * NBLK + bid] = fs;
        psq [(size_t)tid * NBLK + bid] = fq;
    }

    cg::this_grid().sync();

    // ---- Phase 2: blocks 0..255 fold column bid's partials -> mu, inv_std ----
    if (bid < D) {
        const int c = bid;
        // NBLK/4 = 256 quads: exactly one float4 per thread
        f4 vs = ((const f4*)(psum + (size_t)c * NBLK))[tid];
        f4 vq = ((const f4*)(psq  + (size_t)c * NBLK))[tid];
        float s = vs.x + vs.y + vs.z + vs.w;
        float q = vq.x + vq.y + vq.z + vq.w;
        #pragma unroll
        for (int off = 32; off > 0; off >>= 1) {
            s += __shfl_down(s, off, 64);
            q += __shfl_down(q, off, 64);
        }
        __shared__ float ss[4], sq[4];
        if ((tid & 63) == 0) { ss[tid >> 6] = s; sq[tid >> 6] = q; }
        __syncthreads();
        if (tid == 0) {
            float fs = ss[0] + ss[1] + ss[2] + ss[3];
            float fq = sq[0] + sq[1] + sq[2] + sq[3];
            const float invN = 1.0f / (float)NROWS;
            float mu  = fs * invN;
            float var = fmaf(-mu, mu, fq * invN);   // E[x^2] - mu^2
            var = fmaxf(var, VAR_FLOOR);            // floor (never binds for N(0,1))
            stats[c]     = mu;
            stats[D + c] = rsqrtf(var + EPS);
        }
    }

    cg::this_grid().sync();

    // ---- Phase 3: normalize (each thread: 32 float4s at static stride) ----
    {
        const f4 mu4 = ((const f4*)stats)[col4];
        const f4 iv4 = ((const f4*)(stats + D))[col4];
        const size_t base = (size_t)bid * 256 + tid;
        f4* __restrict__ ov = (f4*)out;
        #pragma unroll 4
        for (int k = 0; k < P3_TRIPS; ++k) {
            const size_t e = base + (size_t)k * P3_STRIDE;
            f4 v = xv[e];
            ov[e] = (v - mu4) * iv4;
        }
    }
}

extern "C" void kernel_launch(void* const* d_in, const int* in_sizes, int n_in,
                              void* d_out, int out_size, void* d_ws, size_t ws_size,
                              hipStream_t stream) {
    const float* x   = (const float*)d_in[0];
    float*       out = (float*)d_out;
    float*       ws  = (float*)d_ws;

    float* psum  = ws;                          // NBLK*D floats = 1 MB
    float* psq   = ws + (size_t)NBLK * D;       // 1 MB
    float* stats = psq + (size_t)NBLK * D;      // 2 KB

    void* args[] = { (void*)&x, (void*)&psum, (void*)&psq, (void*)&stats, (void*)&out };
    hipLaunchCooperativeKernel((void*)rsnorm_fused, dim3(NBLK), dim3(256),
                               args, 0, stream);
}

// Round 6
// 71.022 us; speedup vs baseline: 4.1103x; 4.1103x over previous
//
#include <hip/hip_runtime.h>

// RSNorm: x (131072 x 256) f32. Column mean/var (mathematically equal to the
// reference's sequential running-stats scan to <1e-7), then normalize.
// Round-5: exact revert to the round-1 best-measured configuration (70.8 us).
// History: nt-stores (r2) neutral; p3 static-trip unroll (r3) neutral-negative;
// cooperative fusion (r4) 4x regression (cg::grid_sync is ~200us on gfx950).
// Floor arithmetic: 384 MB fabric traffic (x: HBM once + L3 once; out: HBM
// once; x cannot be kept on-chip -- it equals the whole chip's VGPR file) at
// 6.3-7.1 TB/s mixed => 54-61 us + p2 + 2 boundaries => 60-68 us floor.

static constexpr int   D         = 256;
static constexpr int   NROWS     = 131072;
static constexpr float EPS       = 1e-5f;
static constexpr float VAR_FLOOR = 0.001f;

// ---------- Pass 1: per-block column partial sums, transposed output ----------
// Block: 256 threads = 4 row-lanes x 64 col-quads (float4). Each block owns
// rows [bid*rpb, (bid+1)*rpb). Coalesced float4 loads (1 KiB/wave-inst).
// Output layout: psum[col * nblk + bid] (scattered 4B stores, 2 KB/block).
__global__ __launch_bounds__(256) void pass1_partials(const float* __restrict__ x,
                                                      float* __restrict__ psum,
                                                      float* __restrict__ psq,
                                                      int rows_per_blk, int nblk) {
    const int tid    = threadIdx.x;
    const int col4   = tid & 63;   // which float4 of the row
    const int rowoff = tid >> 6;   // 0..3
    const float4* __restrict__ xv = (const float4*)x;
    const size_t base_row = (size_t)blockIdx.x * rows_per_blk + rowoff;

    float4 s = make_float4(0.f, 0.f, 0.f, 0.f);
    float4 q = make_float4(0.f, 0.f, 0.f, 0.f);
    const int iters = rows_per_blk >> 2;
    #pragma unroll 8
    for (int i = 0; i < iters; ++i) {
        float4 v = xv[(base_row + (size_t)i * 4) * (D / 4) + col4];
        s.x += v.x; s.y += v.y; s.z += v.z; s.w += v.w;
        q.x = fmaf(v.x, v.x, q.x);
        q.y = fmaf(v.y, v.y, q.y);
        q.z = fmaf(v.z, v.z, q.z);
        q.w = fmaf(v.w, v.w, q.w);
    }

    __shared__ float ls[4][D];
    __shared__ float lq[4][D];
    ls[rowoff][col4 * 4 + 0] = s.x;
    ls[rowoff][col4 * 4 + 1] = s.y;
    ls[rowoff][col4 * 4 + 2] = s.z;
    ls[rowoff][col4 * 4 + 3] = s.w;
    lq[rowoff][col4 * 4 + 0] = q.x;
    lq[rowoff][col4 * 4 + 1] = q.y;
    lq[rowoff][col4 * 4 + 2] = q.z;
    lq[rowoff][col4 * 4 + 3] = q.w;
    __syncthreads();

    // thread tid reduces column tid across the 4 row-lanes, writes transposed
    float fs = ls[0][tid] + ls[1][tid] + ls[2][tid] + ls[3][tid];
    float fq = lq[0][tid] + lq[1][tid] + lq[2][tid] + lq[3][tid];
    psum[(size_t)tid * nblk + blockIdx.x] = fs;
    psq [(size_t)tid * nblk + blockIdx.x] = fq;
}

// ---------- Pass 2: 256 blocks, block c folds column c -> mu, inv_std ----------
__global__ __launch_bounds__(256) void pass2_finalize(const float* __restrict__ psum,
                                                      const float* __restrict__ psq,
                                                      float* __restrict__ stats,
                                                      int nblk) {
    const int c = blockIdx.x;          // column
    const int t = threadIdx.x;
    float s = 0.f, q = 0.f;
    const int nquads = nblk >> 2;      // nblk is a power of two >= 64
    for (int i = t; i < nquads; i += 256) {
        float4 vs = ((const float4*)(psum + (size_t)c * nblk))[i];
        float4 vq = ((const float4*)(psq  + (size_t)c * nblk))[i];
        s += vs.x + vs.y + vs.z + vs.w;
        q += vq.x + vq.y + vq.z + vq.w;
    }
    // wave reduce (64 lanes)
    #pragma unroll
    for (int off = 32; off > 0; off >>= 1) {
        s += __shfl_down(s, off, 64);
        q += __shfl_down(q, off, 64);
    }
    __shared__ float ss[4], sq[4];
    if ((t & 63) == 0) { ss[t >> 6] = s; sq[t >> 6] = q; }
    __syncthreads();
    if (t == 0) {
        float fs = ss[0] + ss[1] + ss[2] + ss[3];
        float fq = sq[0] + sq[1] + sq[2] + sq[3];
        const float invN = 1.0f / (float)NROWS;
        float mu  = fs * invN;
        float var = fmaf(-mu, mu, fq * invN);   // E[x^2] - mu^2
        var = fmaxf(var, VAR_FLOOR);            // floor (never binds for N(0,1))
        stats[c]     = mu;
        stats[D + c] = rsqrtf(var + EPS);
    }
}

// ---------- Pass 3: out = (x - mu) * inv_std ----------
// Grid-stride over float4 elements; each thread's column-quad (e % 64) is
// invariant because the stride is a multiple of 64, so stats load once.
__global__ __launch_bounds__(256) void pass3_normalize(const float* __restrict__ x,
                                                       const float* __restrict__ stats,
                                                       float* __restrict__ out) {
    const int tid  = threadIdx.x;
    const int col4 = tid & 63;
    const float4 mu4 = ((const float4*)stats)[col4];
    const float4 iv4 = ((const float4*)(stats + D))[col4];

    const size_t total = (size_t)NROWS * (D / 4);
    const size_t G     = (size_t)gridDim.x * blockDim.x;
    const float4* __restrict__ xv = (const float4*)x;
    float4* __restrict__ ov = (float4*)out;

    for (size_t e = (size_t)blockIdx.x * blockDim.x + tid; e < total; e += G) {
        float4 v = xv[e];
        float4 o;
        o.x = (v.x - mu4.x) * iv4.x;
        o.y = (v.y - mu4.y) * iv4.y;
        o.z = (v.z - mu4.z) * iv4.z;
        o.w = (v.w - mu4.w) * iv4.w;
        ov[e] = o;
    }
}

extern "C" void kernel_launch(void* const* d_in, const int* in_sizes, int n_in,
                              void* d_out, int out_size, void* d_ws, size_t ws_size,
                              hipStream_t stream) {
    const float* x   = (const float*)d_in[0];
    float*       out = (float*)d_out;
    float*       ws  = (float*)d_ws;

    // Pick pass-1 block count to fit workspace: nblk*256*2 partials + 512 stats.
    int nblk = 1024;
    while (nblk > 64 && (size_t)(nblk * 2 * D + 2 * D) * sizeof(float) > ws_size)
        nblk >>= 1;
    const int rows_per_blk = NROWS / nblk;

    float* psum  = ws;
    float* psq   = ws + (size_t)nblk * D;
    float* stats = psq + (size_t)nblk * D;

    pass1_partials<<<nblk, 256, 0, stream>>>(x, psum, psq, rows_per_blk, nblk);
    pass2_finalize<<<D, 256, 0, stream>>>(psum, psq, stats, nblk);
    pass3_normalize<<<2048, 256, 0, stream>>>(x, stats, out);
}